// Round 4
// baseline (124.588 us; speedup 1.0000x reference)
//
#include <hip/hip_runtime.h>

// Problem constants (from reference: B=8, N=8192, M=2500, P=10)
#define B_   8
#define N_   8192
#define M_   2500
#define SPP_ 250
#define EPS_ 1e-20f

#define ZP_  64      // p2gt: gt split into 64 chunks of 128
#define ZG_  20      // gt2p: pred split into 20 chunks of 125

// ---- ws layout (floats) ----
#define WS_P2GT  0                    // ZP_*20000 = 1,280,000 partial mins
#define WS_GT2P  1280000              // ZG_*65536 = 1,310,720 partial mins
#define WS_F1P   2590720              // 79 blocks x 16 floats (fff pass-1 partials)
#define WS_RED   2591984              // reduce-kernel partials: 256 + 79 + 79 + 79
#define WS_CNT   2592477              // arrival counter (uint)

// fused_reduce role block counts
#define NB_RGT2P 256
#define NB_RP2GT 79
#define NB_FFF2  79
#define NB_RED   (NB_RGT2P + NB_RP2GT + NB_FFF2)   // 414
// WS_RED sub-offsets
#define RO_GT2P  0
#define RO_P2GT  256
#define RO_EC    335
#define RO_GC    414

__device__ __forceinline__ float wave_sum64(float v) {
    #pragma unroll
    for (int o = 32; o > 0; o >>= 1) v += __shfl_down(v, o, 64);
    return v;
}

// Block sum over 256 threads (4 waves). Result valid on thread 0 only.
__device__ __forceinline__ float block_sum256(float v, float* red4) {
    v = wave_sum64(v);
    int wid  = threadIdx.x >> 6;
    int lane = threadIdx.x & 63;
    if (lane == 0) red4[wid] = v;
    __syncthreads();
    float r = 0.f;
    if (threadIdx.x == 0) r = red4[0] + red4[1] + red4[2] + red4[3];
    __syncthreads();
    return r;
}

// ---- Chamfer: pred -> nearest gt ------------------------------------------
// grid (2, 8, 64): x covers 1280 preds (J=5), b, z = gt chunk of 128.
// Non-atomic per-z partial minima; each slot written by exactly one thread.
__global__ void __launch_bounds__(256) chamfer_p2gt(
        const float* __restrict__ gt, const float* __restrict__ pred,
        float* __restrict__ ws) {
    __shared__ float4 sg[128];
    const int x = blockIdx.x, b = blockIdx.y, z = blockIdx.z;
    const int tid = threadIdx.x;

    // zero the arrival counter for the reduce kernel (runs strictly later)
    if (x == 0 && b == 0 && z == 0 && tid == 0)
        ((unsigned int*)(ws + WS_CNT))[0] = 0u;

    const float* gtb = gt + ((size_t)b * N_ + (size_t)z * 128) * 3;
    if (tid < 128) {
        float gx = gtb[tid * 3 + 0];
        float gy = gtb[tid * 3 + 1];
        float gz = gtb[tid * 3 + 2];
        sg[tid] = make_float4(-2.f * gx, -2.f * gy, -2.f * gz,
                              gx * gx + gy * gy + gz * gz);
    }
    __syncthreads();

    const int base = x * 1280 + tid;
    float px[5], py[5], pz[5], pn[5], best[5];
    #pragma unroll
    for (int j = 0; j < 5; ++j) {
        int idx = base + 256 * j;                 // [0,2560)
        int ic  = idx < M_ ? idx : M_ - 1;        // clamp (dup work, store masked)
        const float* p = pred + ((size_t)b * M_ + ic) * 3;
        px[j] = p[0]; py[j] = p[1]; pz[j] = p[2];
        pn[j] = px[j] * px[j] + py[j] * py[j] + pz[j] * pz[j];
        best[j] = 3.4e38f;
    }
    #pragma unroll 2
    for (int i = 0; i < 128; ++i) {
        float4 g = sg[i];
        #pragma unroll
        for (int j = 0; j < 5; ++j) {
            float v = fmaf(g.x, px[j], fmaf(g.y, py[j], fmaf(g.z, pz[j], g.w)));
            best[j] = fminf(best[j], v);
        }
    }
    float* dst = ws + WS_P2GT + (size_t)z * 20000 + b * M_;
    #pragma unroll
    for (int j = 0; j < 5; ++j) {
        int idx = base + 256 * j;
        if (idx < M_) dst[idx] = fmaxf(best[j] + pn[j], 0.f);
    }
}

// ---- Chamfer: gt -> nearest pred ------------------------------------------
// grid (8, 8, 20): x covers 2048 gts... x*256+tid in [0,2048), J=4 strided 2048.
__global__ void __launch_bounds__(256) chamfer_gt2p(
        const float* __restrict__ gt, const float* __restrict__ pred,
        float* __restrict__ ws) {
    __shared__ float4 sp[125];
    const int x = blockIdx.x, b = blockIdx.y, z = blockIdx.z;
    const int tid = threadIdx.x;

    const float* pb = pred + ((size_t)b * M_ + (size_t)z * 125) * 3;
    if (tid < 125) {
        float vx = pb[tid * 3 + 0];
        float vy = pb[tid * 3 + 1];
        float vz = pb[tid * 3 + 2];
        sp[tid] = make_float4(-2.f * vx, -2.f * vy, -2.f * vz,
                              vx * vx + vy * vy + vz * vz);
    }
    __syncthreads();

    const int t = x * 256 + tid;                  // [0,2048)
    float gx[4], gy[4], gz[4], gn[4], best[4];
    #pragma unroll
    for (int j = 0; j < 4; ++j) {
        int idx = t + 2048 * j;                   // covers [0,8192) exactly
        const float* g = gt + ((size_t)b * N_ + idx) * 3;
        gx[j] = g[0]; gy[j] = g[1]; gz[j] = g[2];
        gn[j] = gx[j] * gx[j] + gy[j] * gy[j] + gz[j] * gz[j];
        best[j] = 3.4e38f;
    }
    #pragma unroll 2
    for (int i = 0; i < 125; ++i) {
        float4 p = sp[i];
        #pragma unroll
        for (int j = 0; j < 4; ++j) {
            float v = fmaf(p.x, gx[j], fmaf(p.y, gy[j], fmaf(p.z, gz[j], p.w)));
            best[j] = fminf(best[j], v);
        }
    }
    float* dst = ws + WS_GT2P + (size_t)z * 65536 + b * N_;
    #pragma unroll
    for (int j = 0; j < 4; ++j) {
        int idx = t + 2048 * j;
        dst[idx] = fmaxf(best[j] + gn[j], 0.f);
    }
}

// ---- FFF pass 1: per-block partials, non-atomic ---------------------------
// grid 79. Block k writes 16 floats at WS_F1P + 16k:
// [0]=sumE [1]=sumG [2]=sumMC [3]=sumST [4]=sumF [5..12]=per-batch sum sqrt(A2)
__global__ void __launch_bounds__(256) fff_pass1(
        const float* __restrict__ fff, float* __restrict__ ws) {
    __shared__ float red4[4];
    __shared__ float sA[B_];
    const int k = blockIdx.x;
    const int tid = threadIdx.x;
    const int i = k * 256 + tid;

    if (tid < B_) sA[tid] = 0.f;
    __syncthreads();

    float sE = 0.f, sG = 0.f, sMC = 0.f, sST = 0.f, sF = 0.f;
    if (i < B_ * M_) {
        const int b = i / M_;
        const int m = i - b * M_;
        const float* f = fff + (size_t)i * 3;
        float E = f[0], F = f[1], G = f[2];
        sE = E; sG = G;
        float A2  = fmaxf(E * G - F * F, 0.f);
        float inv = 1.f / (A2 + EPS_);
        sST = (E - G) * (E - G) * inv;
        sF  = F * F * inv;
        atomicAdd(&sA[b], sqrtf(A2));
        if ((b & 1) == 0) {
            const float* f2 = fff + ((size_t)(b + 1) * M_ + m) * 3;
            float dE = E - f2[0], dF = F - f2[1], dG = G - f2[2];
            sMC = dE * dE + 2.f * dF * dF + dG * dG;
        }
    }
    float rE  = block_sum256(sE,  red4);
    float rG  = block_sum256(sG,  red4);
    float rMC = block_sum256(sMC, red4);
    float rST = block_sum256(sST, red4);
    float rF  = block_sum256(sF,  red4);
    float* out = ws + WS_F1P + (size_t)k * 16;
    if (tid == 0) {
        out[0] = rE; out[1] = rG; out[2] = rMC; out[3] = rST; out[4] = rF;
    }
    __syncthreads();   // sA atomics all complete (threads passed block_sum syncs)
    if (tid < B_) out[5 + tid] = sA[tid];
}

// ---- reduce: min-over-z for both directions + fff pass 2 + finalize -------
__global__ void __launch_bounds__(256) fused_reduce(
        const float* __restrict__ fff, const float* __restrict__ A_gt,
        float* __restrict__ ws, float* __restrict__ out) {
    __shared__ float red4[4];
    __shared__ float bc2[2];
    const int bid = blockIdx.x;
    const int tid = threadIdx.x;
    float* redp = ws + WS_RED;
    const float* f1p = ws + WS_F1P;

    if (bid < NB_RGT2P) {
        // gt2p: min over 20 z-chunks, block-sum, store partial
        const int o = bid * 256 + tid;                 // [0,65536)
        const float* src = ws + WS_GT2P + o;
        float m = src[0];
        #pragma unroll
        for (int z = 1; z < ZG_; ++z) m = fminf(m, src[(size_t)z * 65536]);
        float r = block_sum256(m, red4);
        if (tid == 0) redp[RO_GT2P + bid] = r;
    } else if (bid < NB_RGT2P + NB_RP2GT) {
        // p2gt: min over 64 z-chunks
        const int kb = bid - NB_RGT2P;
        const int o = kb * 256 + tid;                  // [0,20224)
        float s = 0.f;
        if (o < 20000) {
            const float* src = ws + WS_P2GT + o;
            float m = src[0];
            #pragma unroll
            for (int z = 1; z < ZP_; ++z) m = fminf(m, src[(size_t)z * 20000]);
            s = m;
        }
        float r = block_sum256(s, red4);
        if (tid == 0) redp[RO_P2GT + kb] = r;
    } else {
        // fff pass 2: means from pass-1 partials (prior dispatch)
        const int kb = bid - NB_RGT2P - NB_RP2GT;
        float pe = 0.f, pg = 0.f;
        if (tid < 79) { pe = f1p[tid * 16 + 0]; pg = f1p[tid * 16 + 1]; }
        float rE = block_sum256(pe, red4);
        float rG = block_sum256(pg, red4);
        if (tid == 0) { bc2[0] = rE; bc2[1] = rG; }
        __syncthreads();
        const float mE = bc2[0] * (1.f / 20000.f);
        const float mG = bc2[1] * (1.f / 20000.f);

        const int i = kb * 256 + tid;
        float sEC = 0.f, sGC = 0.f;
        if (i < B_ * M_) {
            const float* f = fff + (size_t)i * 3;
            float E = f[0], F = f[1], G = f[2];
            float A2  = fmaxf(E * G - F * F, 0.f);
            float inv = 1.f / (A2 + EPS_);
            sEC = (E - mE) * (E - mE) * inv;
            sGC = (G - mG) * (G - mG) * inv;
        }
        float rEC = block_sum256(sEC, red4);
        float rGC = block_sum256(sGC, red4);
        if (tid == 0) { redp[RO_EC + kb] = rEC; redp[RO_GC + kb] = rGC; }
    }

    // ---- arrival counter; last block finalizes
    __syncthreads();
    if (tid == 0) __threadfence();   // publish this block's partial
    __syncthreads();
    unsigned int* cnt = (unsigned int*)(ws + WS_CNT);
    __shared__ unsigned int old_s;
    if (tid == 0)
        old_s = __hip_atomic_fetch_add(cnt, 1u, __ATOMIC_ACQ_REL,
                                       __HIP_MEMORY_SCOPE_AGENT);
    __syncthreads();
    if (old_s == (unsigned int)(NB_RED - 1)) {
        // last block: sum all partials and write the scalar loss
        float v;
        v = (tid < NB_RGT2P) ? redp[RO_GT2P + tid] : 0.f;
        float sGT2P = block_sum256(v, red4);
        v = (tid < 79) ? redp[RO_P2GT + tid] : 0.f;
        float sP2GT = block_sum256(v, red4);
        v = (tid < 79) ? redp[RO_EC + tid] : 0.f;
        float sEC = block_sum256(v, red4);
        v = (tid < 79) ? redp[RO_GC + tid] : 0.f;
        float sGC = block_sum256(v, red4);
        v = (tid < 79) ? f1p[tid * 16 + 2] : 0.f;
        float sMC = block_sum256(v, red4);
        v = (tid < 79) ? f1p[tid * 16 + 3] : 0.f;
        float sST = block_sum256(v, red4);
        v = (tid < 79) ? f1p[tid * 16 + 4] : 0.f;
        float sF = block_sum256(v, red4);
        float sAb[B_];
        #pragma unroll
        for (int b = 0; b < B_; ++b) {
            v = (tid < 79) ? f1p[tid * 16 + 5 + b] : 0.f;
            sAb[b] = block_sum256(v, red4);
        }
        if (tid == 0) {
            float L_chd = sP2GT * (1.f / 20000.f) + sGT2P * (1.f / 65536.f);
            float L_mc  = sMC * (1.f / 10000.f);
            float L_sc  = (sST + sF + sEC + sGC) * (1.f / 20000.f);
            float L_olap = 0.f;
            #pragma unroll
            for (int b = 0; b < B_; ++b) {
                float At = sAb[b] * (1.f / (float)SPP_);
                float r  = fmaxf(0.f, At - A_gt[b]);
                L_olap += r * r;
            }
            L_olap *= (1.f / (float)B_);
            out[0] = L_chd + L_mc + L_sc + L_olap;
        }
    }
}

extern "C" void kernel_launch(void* const* d_in, const int* in_sizes, int n_in,
                              void* d_out, int out_size, void* d_ws, size_t ws_size,
                              hipStream_t stream) {
    const float* pc_gt   = (const float*)d_in[0];   // (8, 8192, 3)
    const float* pc_pred = (const float*)d_in[1];   // (8, 2500, 3)
    const float* fff     = (const float*)d_in[2];   // (8, 2500, 3)
    const float* A_gt    = (const float*)d_in[3];   // (8,)
    float* ws  = (float*)d_ws;                      // ~10.4 MB used
    float* out = (float*)d_out;

    chamfer_p2gt<<<dim3(2, 8, 64), 256, 0, stream>>>(pc_gt, pc_pred, ws);
    chamfer_gt2p<<<dim3(8, 8, 20), 256, 0, stream>>>(pc_gt, pc_pred, ws);
    fff_pass1   <<<79, 256, 0, stream>>>(fff, ws);
    fused_reduce<<<NB_RED, 256, 0, stream>>>(fff, A_gt, ws, out);
}

// Round 5
// 123.178 us; speedup vs baseline: 1.0114x; 1.0114x over previous
//
#include <hip/hip_runtime.h>

// Problem constants (from reference: B=8, N=8192, M=2500, P=10)
#define B_   8
#define N_   8192
#define M_   2500
#define SPP_ 250
#define EPS_ 1e-20f
#define BIGF 1e30f

// ---- kernel-1 roles ----
// p2gt: z in [0,4) gt-chunks of 2048; 8 b; 20 m-blocks of 128 preds
#define NB_P2GT 640
// gt2p: 8 b x 64 m-blocks of 128 gts; all 2500 preds per block
#define NB_GT2P 512
#define NB_FFF1 79
#define NB_K1   (NB_P2GT + NB_GT2P + NB_FFF1)   // 1231

// ---- kernel-2 roles ----
#define NB_RP2  79
#define NB_FFF2 79
#define NB_K2   (NB_RP2 + NB_FFF2)              // 158

// ---- ws layout (floats) ----
#define WS_P2GT 0            // 4 z-chunks x 20000 partial minima (unclamped)
#define WS_G2P  80000        // 512 per-block gt2p sums
#define WS_F1P  80512        // 79 x 16 fff pass-1 partials
#define WS_RED  81776        // kernel-2 partials: 79 p2 + 79 EC + 79 GC
#define RO_P2   0
#define RO_EC   79
#define RO_GC   158
#define WS_CNT  82013        // arrival counter (uint)

typedef __attribute__((ext_vector_type(8)))  short short8_t;
typedef __attribute__((ext_vector_type(4)))  float float4_t;

__device__ __forceinline__ unsigned pack_bf2(float lo, float hi) {
    unsigned a = __float_as_uint(lo);
    unsigned b = __float_as_uint(hi);
    a = (a + 0x7FFFu + ((a >> 16) & 1u)) >> 16;
    b = (b + 0x7FFFu + ((b >> 16) & 1u)) & 0xFFFF0000u;
    return a | b;
}
__device__ __forceinline__ short bf16s(float x) {
    unsigned a = __float_as_uint(x);
    return (short)((a + 0x7FFFu + ((a >> 16) & 1u)) >> 16);
}

__device__ __forceinline__ float wave_sum64(float v) {
    #pragma unroll
    for (int o = 32; o > 0; o >>= 1) v += __shfl_down(v, o, 64);
    return v;
}
__device__ __forceinline__ float block_sum256(float v, float* red4) {
    v = wave_sum64(v);
    int wid  = threadIdx.x >> 6;
    int lane = threadIdx.x & 63;
    if (lane == 0) red4[wid] = v;
    __syncthreads();
    float r = 0.f;
    if (threadIdx.x == 0) r = red4[0] + red4[1] + red4[2] + red4[3];
    __syncthreads();
    return r;
}

// min over the 16 lanes of each quad (quad-local butterfly, masks < 16)
__device__ __forceinline__ void quad_min4(float4_t& c) {
    #pragma unroll
    for (int m = 1; m < 16; m <<= 1) {
        c.x = fminf(c.x, __shfl_xor(c.x, m, 64));
        c.y = fminf(c.y, __shfl_xor(c.y, m, 64));
        c.z = fminf(c.z, __shfl_xor(c.z, m, 64));
        c.w = fminf(c.w, __shfl_xor(c.w, m, 64));
    }
}

// ============================================================================
// Kernel 1: MFMA chamfer (both directions) + fff pass 1.
// d^2 cross-term via bf16 MFMA: C[m][n] = sum_k A[m][k] B[k][n] with
// K=4 used (x,y,z,1): A = {c0,c1,c2,1}, B = {-2d0,-2d1,-2d2,|d|^2}.
// A-layout: A[m=lane&15][k=quad*8+j]; B[k=quad*8+j][n=lane&15];
// C/D: col=lane&15, row=quad*4+reg (guide-verified, gfx950).
// ============================================================================
__global__ void __launch_bounds__(256) k1_main(
        const float* __restrict__ gt, const float* __restrict__ pred,
        const float* __restrict__ fff, float* __restrict__ ws) {
    __shared__ uint2 spts[2512];     // packed bf16 {-2x,-2y}{-2z,n2} per point
    __shared__ float saux[144];      // [0..127] norms, [128..143] block partials

    const int bid = blockIdx.x;
    const int tid = threadIdx.x;
    const int lane = tid & 63;
    const int w    = tid >> 6;       // wave 0..3
    const int quad = lane >> 4;
    const int l15  = lane & 15;

    if (bid == 0 && tid == 0) ((unsigned*)(ws + WS_CNT))[0] = 0u;

    if (bid < NB_P2GT + NB_GT2P) {
        // ---------------- common chamfer setup ----------------
        const bool is_p2gt = bid < NB_P2GT;
        int b, mblk, z;
        const float* apts;   // A-side source points
        const float* bpts;   // B-side (staged) source points
        int nstage, ntiles, abase;
        if (is_p2gt) {
            z = bid / 160; int rem = bid % 160;
            b = rem / 20;  mblk = rem % 20;
            apts = pred + (size_t)b * M_ * 3;
            bpts = gt   + ((size_t)b * N_ + (size_t)z * 2048) * 3;
            nstage = 2048; ntiles = 128;
            abase = mblk * 128 + w * 32;          // pred base for this wave
        } else {
            int r = bid - NB_P2GT;
            z = 0; b = r >> 6; mblk = r & 63;
            apts = gt   + (size_t)b * N_ * 3;
            bpts = pred + (size_t)b * M_ * 3;
            nstage = 2512; ntiles = 157;
            abase = mblk * 128 + w * 32;          // gt base for this wave
        }

        // stage B-side points into LDS (packed bf16, -2x folded, norm in w)
        const int blim = is_p2gt ? 2048 : M_;
        for (int i = tid; i < nstage; i += 256) {
            float x = 0.f, y = 0.f, zc = 0.f, n2 = BIGF;
            if (i < blim) {
                x = bpts[i * 3 + 0]; y = bpts[i * 3 + 1]; zc = bpts[i * 3 + 2];
                n2 = x * x + y * y + zc * zc;
            }
            uint2 q;
            q.x = pack_bf2(-2.f * x, -2.f * y);
            q.y = pack_bf2(-2.f * zc, n2);
            spts[i] = q;
        }

        // build A fragments (2 m-tiles of 16 per wave) + stash fp32 norms
        short8_t af0 = {0,0,0,0,0,0,0,0}, af1 = {0,0,0,0,0,0,0,0};
        if (lane < 16) {
            int m0 = abase + l15;
            int m1 = abase + 16 + l15;
            int lim = is_p2gt ? M_ : N_;
            int c0 = m0 < lim ? m0 : lim - 1;
            int c1 = m1 < lim ? m1 : lim - 1;
            float x0 = apts[c0*3+0], y0 = apts[c0*3+1], z0 = apts[c0*3+2];
            float x1 = apts[c1*3+0], y1 = apts[c1*3+1], z1 = apts[c1*3+2];
            af0[0] = bf16s(x0); af0[1] = bf16s(y0); af0[2] = bf16s(z0);
            af0[3] = (short)0x3F80;   // 1.0 bf16
            af1[0] = bf16s(x1); af1[1] = bf16s(y1); af1[2] = bf16s(z1);
            af1[3] = (short)0x3F80;
            saux[w * 32 + l15]      = x0*x0 + y0*y0 + z0*z0;
            saux[w * 32 + 16 + l15] = x1*x1 + y1*y1 + z1*z1;
        }
        __syncthreads();   // staging + norm stash complete

        const float4_t zc4 = {0.f, 0.f, 0.f, 0.f};
        float4_t c0 = {BIGF, BIGF, BIGF, BIGF};
        float4_t c1 = {BIGF, BIGF, BIGF, BIGF};

        #pragma unroll 2
        for (int i = 0; i < ntiles; ++i) {
            short8_t bf = {0,0,0,0,0,0,0,0};
            if (lane < 16) {
                uint2 q = spts[i * 16 + l15];
                bf[0] = (short)(q.x & 0xFFFF); bf[1] = (short)(q.x >> 16);
                bf[2] = (short)(q.y & 0xFFFF); bf[3] = (short)(q.y >> 16);
            }
            float4_t d0 = __builtin_amdgcn_mfma_f32_16x16x32_bf16(af0, bf, zc4, 0, 0, 0);
            float4_t d1 = __builtin_amdgcn_mfma_f32_16x16x32_bf16(af1, bf, zc4, 0, 0, 0);
            c0.x = fminf(c0.x, d0.x); c0.y = fminf(c0.y, d0.y);
            c0.z = fminf(c0.z, d0.z); c0.w = fminf(c0.w, d0.w);
            c1.x = fminf(c1.x, d1.x); c1.y = fminf(c1.y, d1.y);
            c1.z = fminf(c1.z, d1.z); c1.w = fminf(c1.w, d1.w);
        }

        // reduce over the 16 columns within each quad
        quad_min4(c0);
        quad_min4(c1);

        if (is_p2gt) {
            // write unclamped (cross_min + |p|^2) per pred into z-partials
            if (l15 == 0) {
                float* dst = ws + WS_P2GT + (size_t)z * 20000 + b * M_;
                float vals0[4] = {c0.x, c0.y, c0.z, c0.w};
                float vals1[4] = {c1.x, c1.y, c1.z, c1.w};
                #pragma unroll
                for (int r = 0; r < 4; ++r) {
                    int row = quad * 4 + r;
                    int m0 = abase + row;
                    int m1 = abase + 16 + row;
                    if (m0 < M_) dst[m0] = vals0[r] + saux[w * 32 + row];
                    if (m1 < M_) dst[m1] = vals1[r] + saux[w * 32 + 16 + row];
                }
            }
        } else {
            // final minima for this block's 128 gts: clamp + sum
            float s = 0.f;
            if (l15 == 0) {
                float vals0[4] = {c0.x, c0.y, c0.z, c0.w};
                float vals1[4] = {c1.x, c1.y, c1.z, c1.w};
                #pragma unroll
                for (int r = 0; r < 4; ++r) {
                    int row = quad * 4 + r;
                    s += fmaxf(vals0[r] + saux[w * 32 + row], 0.f);
                    s += fmaxf(vals1[r] + saux[w * 32 + 16 + row], 0.f);
                }
                saux[128 + w * 4 + quad] = s;
            }
            __syncthreads();
            if (tid == 0) {
                float t = 0.f;
                #pragma unroll
                for (int i = 0; i < 16; ++i) t += saux[128 + i];
                ws[WS_G2P + (bid - NB_P2GT)] = t;
            }
        }
    } else {
        // ---------------- fff pass 1 ----------------
        const int kb = bid - NB_P2GT - NB_GT2P;
        const int i  = kb * 256 + tid;
        float* red4 = saux;           // [0..3]
        float* sA   = saux + 8;       // [8..15]
        if (tid < B_) sA[tid] = 0.f;
        __syncthreads();

        float sE = 0.f, sG = 0.f, sMC = 0.f, sST = 0.f, sF = 0.f;
        if (i < B_ * M_) {
            const int b = i / M_;
            const int m = i - b * M_;
            const float* f = fff + (size_t)i * 3;
            float E = f[0], F = f[1], G = f[2];
            sE = E; sG = G;
            float A2  = fmaxf(E * G - F * F, 0.f);
            float inv = 1.f / (A2 + EPS_);
            sST = (E - G) * (E - G) * inv;
            sF  = F * F * inv;
            atomicAdd(&sA[b], sqrtf(A2));
            if ((b & 1) == 0) {
                const float* f2 = fff + ((size_t)(b + 1) * M_ + m) * 3;
                float dE = E - f2[0], dF = F - f2[1], dG = G - f2[2];
                sMC = dE * dE + 2.f * dF * dF + dG * dG;
            }
        }
        float rE  = block_sum256(sE,  red4);
        float rG  = block_sum256(sG,  red4);
        float rMC = block_sum256(sMC, red4);
        float rST = block_sum256(sST, red4);
        float rF  = block_sum256(sF,  red4);
        float* outp = ws + WS_F1P + (size_t)kb * 16;
        if (tid == 0) {
            outp[0] = rE; outp[1] = rG; outp[2] = rMC; outp[3] = rST; outp[4] = rF;
        }
        __syncthreads();
        if (tid < B_) outp[5 + tid] = sA[tid];
    }
}

// ============================================================================
// Kernel 2: p2gt min-over-z + fff pass 2 + last-block finalize.
// ============================================================================
__global__ void __launch_bounds__(256) k2_reduce(
        const float* __restrict__ fff, const float* __restrict__ A_gt,
        float* __restrict__ ws, float* __restrict__ out) {
    __shared__ float red4[4];
    __shared__ float bc2[2];
    const int bid = blockIdx.x;
    const int tid = threadIdx.x;
    float* redp = ws + WS_RED;
    const float* f1p = ws + WS_F1P;

    if (bid < NB_RP2) {
        const int o = bid * 256 + tid;               // [0,20224)
        float s = 0.f;
        if (o < 20000) {
            const float* src = ws + WS_P2GT + o;
            float m = src[0];
            m = fminf(m, src[20000]);
            m = fminf(m, src[40000]);
            m = fminf(m, src[60000]);
            s = fmaxf(m, 0.f);
        }
        float r = block_sum256(s, red4);
        if (tid == 0) redp[RO_P2 + bid] = r;
    } else {
        const int kb = bid - NB_RP2;
        float pe = 0.f, pg = 0.f;
        if (tid < 79) { pe = f1p[tid * 16 + 0]; pg = f1p[tid * 16 + 1]; }
        float rE = block_sum256(pe, red4);
        float rG = block_sum256(pg, red4);
        if (tid == 0) { bc2[0] = rE; bc2[1] = rG; }
        __syncthreads();
        const float mE = bc2[0] * (1.f / 20000.f);
        const float mG = bc2[1] * (1.f / 20000.f);

        const int i = kb * 256 + tid;
        float sEC = 0.f, sGC = 0.f;
        if (i < B_ * M_) {
            const float* f = fff + (size_t)i * 3;
            float E = f[0], F = f[1], G = f[2];
            float A2  = fmaxf(E * G - F * F, 0.f);
            float inv = 1.f / (A2 + EPS_);
            sEC = (E - mE) * (E - mE) * inv;
            sGC = (G - mG) * (G - mG) * inv;
        }
        float rEC = block_sum256(sEC, red4);
        float rGC = block_sum256(sGC, red4);
        if (tid == 0) { redp[RO_EC + kb] = rEC; redp[RO_GC + kb] = rGC; }
    }

    // ---- arrival counter; last block finalizes ----
    __syncthreads();
    if (tid == 0) __threadfence();
    __syncthreads();
    __shared__ unsigned old_s;
    if (tid == 0)
        old_s = __hip_atomic_fetch_add((unsigned*)(ws + WS_CNT), 1u,
                                       __ATOMIC_ACQ_REL, __HIP_MEMORY_SCOPE_AGENT);
    __syncthreads();
    if (old_s == (unsigned)(NB_K2 - 1)) {
        const float* g2p = ws + WS_G2P;
        float v;
        v = g2p[tid] + g2p[tid + 256];
        float sGT2P = block_sum256(v, red4);
        v = (tid < 79) ? redp[RO_P2 + tid] : 0.f;
        float sP2GT = block_sum256(v, red4);
        v = (tid < 79) ? redp[RO_EC + tid] : 0.f;
        float sEC = block_sum256(v, red4);
        v = (tid < 79) ? redp[RO_GC + tid] : 0.f;
        float sGC = block_sum256(v, red4);
        v = (tid < 79) ? f1p[tid * 16 + 2] : 0.f;
        float sMC = block_sum256(v, red4);
        v = (tid < 79) ? f1p[tid * 16 + 3] : 0.f;
        float sST = block_sum256(v, red4);
        v = (tid < 79) ? f1p[tid * 16 + 4] : 0.f;
        float sF = block_sum256(v, red4);
        float sAb[B_];
        #pragma unroll
        for (int b = 0; b < B_; ++b) {
            v = (tid < 79) ? f1p[tid * 16 + 5 + b] : 0.f;
            sAb[b] = block_sum256(v, red4);
        }
        if (tid == 0) {
            float L_chd = sP2GT * (1.f / 20000.f) + sGT2P * (1.f / 65536.f);
            float L_mc  = sMC * (1.f / 10000.f);
            float L_sc  = (sST + sF + sEC + sGC) * (1.f / 20000.f);
            float L_olap = 0.f;
            #pragma unroll
            for (int b = 0; b < B_; ++b) {
                float At = sAb[b] * (1.f / (float)SPP_);
                float r  = fmaxf(0.f, At - A_gt[b]);
                L_olap += r * r;
            }
            L_olap *= (1.f / (float)B_);
            out[0] = L_chd + L_mc + L_sc + L_olap;
        }
    }
}

extern "C" void kernel_launch(void* const* d_in, const int* in_sizes, int n_in,
                              void* d_out, int out_size, void* d_ws, size_t ws_size,
                              hipStream_t stream) {
    const float* pc_gt   = (const float*)d_in[0];   // (8, 8192, 3)
    const float* pc_pred = (const float*)d_in[1];   // (8, 2500, 3)
    const float* fff     = (const float*)d_in[2];   // (8, 2500, 3)
    const float* A_gt    = (const float*)d_in[3];   // (8,)
    float* ws  = (float*)d_ws;                      // ~330 KB used
    float* out = (float*)d_out;

    k1_main  <<<NB_K1, 256, 0, stream>>>(pc_gt, pc_pred, fff, ws);
    k2_reduce<<<NB_K2, 256, 0, stream>>>(fff, A_gt, ws, out);
}

// Round 6
// 121.593 us; speedup vs baseline: 1.0246x; 1.0130x over previous
//
#include <hip/hip_runtime.h>

// Problem constants (from reference: B=8, N=8192, M=2500, P=10)
#define B_   8
#define N_   8192
#define M_   2500
#define SPP_ 250
#define EPS_ 1e-20f
#define BIGF 1e30f

// ---- kernel-1 roles ----
#define NB_P2GT 640    // 4 z-chunks of 2048 gts x 8 b x 20 m-blocks of 128 preds
#define NB_GT2P 512    // 8 b x 64 m-blocks of 128 gts; all 2500 preds staged
#define NB_FFF1 79
#define NB_K1   (NB_P2GT + NB_GT2P + NB_FFF1)   // 1231

// ---- kernel-2 roles ----
#define NB_RP2  79
#define NB_FFF2 79
#define NB_K2   (NB_RP2 + NB_FFF2)              // 158

// ---- ws layout (floats) ----
#define WS_P2GT 0            // 4 z-chunks x 20000 partial minima (unclamped)
#define WS_G2P  80000        // 512 per-block gt2p sums
#define WS_F1P  80512        // 79 x 16 fff pass-1 partials
#define WS_RED  81776        // kernel-2 partials: 79 p2 + 79 EC + 79 GC
#define RO_P2   0
#define RO_EC   79
#define RO_GC   158
#define WS_CNT  82013        // arrival counter (uint)

typedef __attribute__((ext_vector_type(8)))  short short8_t;
typedef __attribute__((ext_vector_type(4)))  int   int4_t;
typedef __attribute__((ext_vector_type(4)))  float float4_t;

__device__ __forceinline__ unsigned pack_bf2(float lo, float hi) {
    unsigned a = __float_as_uint(lo);
    unsigned b = __float_as_uint(hi);
    a = (a + 0x7FFFu + ((a >> 16) & 1u)) >> 16;
    b = (b + 0x7FFFu + ((b >> 16) & 1u)) & 0xFFFF0000u;
    return a | b;
}
__device__ __forceinline__ short bf16s(float x) {
    unsigned a = __float_as_uint(x);
    return (short)((a + 0x7FFFu + ((a >> 16) & 1u)) >> 16);
}

__device__ __forceinline__ float wave_sum64(float v) {
    #pragma unroll
    for (int o = 32; o > 0; o >>= 1) v += __shfl_down(v, o, 64);
    return v;
}
__device__ __forceinline__ float block_sum256(float v, float* red4) {
    v = wave_sum64(v);
    int wid  = threadIdx.x >> 6;
    int lane = threadIdx.x & 63;
    if (lane == 0) red4[wid] = v;
    __syncthreads();
    float r = 0.f;
    if (threadIdx.x == 0) r = red4[0] + red4[1] + red4[2] + red4[3];
    __syncthreads();
    return r;
}

// min over the 16 lanes of each quad (quad-local butterfly, masks < 16)
__device__ __forceinline__ void quad_min4(float4_t& c) {
    #pragma unroll
    for (int m = 1; m < 16; m <<= 1) {
        c.x = fminf(c.x, __shfl_xor(c.x, m, 64));
        c.y = fminf(c.y, __shfl_xor(c.y, m, 64));
        c.z = fminf(c.z, __shfl_xor(c.z, m, 64));
        c.w = fminf(c.w, __shfl_xor(c.w, m, 64));
    }
}

// ============================================================================
// Kernel 1: MFMA chamfer (both directions) + fff pass 1.
// Cross-term via bf16 MFMA, K=4 used of 32: A={x,y,z,1}, B={-2bx,-2by,-2bz,|b|^2}.
// Inner loop: since A[k>=4] == 0 exactly, B's k>=4 content may be ANY FINITE
// value -> all 64 lanes ds_read_b64 the packed shorts and bit-cast into the
// fragment (no unpack VALU, no lane predication). Reused coords (finite) fill
// bf[4..7] so no Inf/NaN can poison the MFMA sum.
// ============================================================================
__global__ void __launch_bounds__(256) k1_main(
        const float* __restrict__ gt, const float* __restrict__ pred,
        const float* __restrict__ fff, float* __restrict__ ws) {
    __shared__ uint2 spts[2512];     // packed bf16 {-2x,-2y}{-2z,n2} per point
    __shared__ float saux[144];      // [0..127] norms, [128..143] block partials

    const int bid = blockIdx.x;
    const int tid = threadIdx.x;
    const int lane = tid & 63;
    const int w    = tid >> 6;       // wave 0..3
    const int quad = lane >> 4;
    const int l15  = lane & 15;

    if (bid == 0 && tid == 0) ((unsigned*)(ws + WS_CNT))[0] = 0u;

    if (bid < NB_P2GT + NB_GT2P) {
        // ---------------- common chamfer setup ----------------
        const bool is_p2gt = bid < NB_P2GT;
        int b, mblk, z;
        const float* apts;   // A-side source points
        const float* bpts;   // B-side (staged) source points
        int nstage, ntiles, abase;
        if (is_p2gt) {
            z = bid / 160; int rem = bid % 160;
            b = rem / 20;  mblk = rem % 20;
            apts = pred + (size_t)b * M_ * 3;
            bpts = gt   + ((size_t)b * N_ + (size_t)z * 2048) * 3;
            nstage = 2048; ntiles = 128;
            abase = mblk * 128 + w * 32;
        } else {
            int r = bid - NB_P2GT;
            z = 0; b = r >> 6; mblk = r & 63;
            apts = gt   + (size_t)b * N_ * 3;
            bpts = pred + (size_t)b * M_ * 3;
            nstage = 2512; ntiles = 157;
            abase = mblk * 128 + w * 32;
        }

        // stage B-side points into LDS (packed bf16, -2x folded, norm in w)
        const int blim = is_p2gt ? 2048 : M_;
        for (int i = tid; i < nstage; i += 256) {
            float x = 0.f, y = 0.f, zc = 0.f, n2 = BIGF;
            if (i < blim) {
                x = bpts[i * 3 + 0]; y = bpts[i * 3 + 1]; zc = bpts[i * 3 + 2];
                n2 = x * x + y * y + zc * zc;
            }
            uint2 q;
            q.x = pack_bf2(-2.f * x, -2.f * y);
            q.y = pack_bf2(-2.f * zc, n2);
            spts[i] = q;
        }

        // build A fragments (2 m-tiles of 16 per wave) + stash fp32 norms
        short8_t af0 = {0,0,0,0,0,0,0,0}, af1 = {0,0,0,0,0,0,0,0};
        if (lane < 16) {
            int m0 = abase + l15;
            int m1 = abase + 16 + l15;
            int lim = is_p2gt ? M_ : N_;
            int c0 = m0 < lim ? m0 : lim - 1;
            int c1 = m1 < lim ? m1 : lim - 1;
            float x0 = apts[c0*3+0], y0 = apts[c0*3+1], z0 = apts[c0*3+2];
            float x1 = apts[c1*3+0], y1 = apts[c1*3+1], z1 = apts[c1*3+2];
            af0[0] = bf16s(x0); af0[1] = bf16s(y0); af0[2] = bf16s(z0);
            af0[3] = (short)0x3F80;   // 1.0 bf16
            af1[0] = bf16s(x1); af1[1] = bf16s(y1); af1[2] = bf16s(z1);
            af1[3] = (short)0x3F80;
            saux[w * 32 + l15]      = x0*x0 + y0*y0 + z0*z0;
            saux[w * 32 + 16 + l15] = x1*x1 + y1*y1 + z1*z1;
        }
        __syncthreads();   // staging + norm stash complete

        const float4_t zc4 = {0.f, 0.f, 0.f, 0.f};
        float4_t c0 = {BIGF, BIGF, BIGF, BIGF};
        float4_t c1 = {BIGF, BIGF, BIGF, BIGF};
        const uint2* bsrc = spts + l15;    // all lanes; quads duplicate = bcast

        #pragma unroll 8
        for (int i = 0; i < ntiles; ++i) {
            uint2 q = bsrc[i * 16];
            int4_t bi;
            bi.x = (int)q.x; bi.y = (int)q.y;
            bi.z = (int)q.x; bi.w = (int)q.y;   // finite garbage for k>=4
            short8_t bf = __builtin_bit_cast(short8_t, bi);
            float4_t d0 = __builtin_amdgcn_mfma_f32_16x16x32_bf16(af0, bf, zc4, 0, 0, 0);
            float4_t d1 = __builtin_amdgcn_mfma_f32_16x16x32_bf16(af1, bf, zc4, 0, 0, 0);
            c0.x = fminf(c0.x, d0.x); c0.y = fminf(c0.y, d0.y);
            c0.z = fminf(c0.z, d0.z); c0.w = fminf(c0.w, d0.w);
            c1.x = fminf(c1.x, d1.x); c1.y = fminf(c1.y, d1.y);
            c1.z = fminf(c1.z, d1.z); c1.w = fminf(c1.w, d1.w);
        }

        // reduce over the 16 columns within each quad
        quad_min4(c0);
        quad_min4(c1);

        if (is_p2gt) {
            // write unclamped (cross_min + |p|^2) per pred into z-partials
            if (l15 == 0) {
                float* dst = ws + WS_P2GT + (size_t)z * 20000 + b * M_;
                float vals0[4] = {c0.x, c0.y, c0.z, c0.w};
                float vals1[4] = {c1.x, c1.y, c1.z, c1.w};
                #pragma unroll
                for (int r = 0; r < 4; ++r) {
                    int row = quad * 4 + r;
                    int m0 = abase + row;
                    int m1 = abase + 16 + row;
                    if (m0 < M_) dst[m0] = vals0[r] + saux[w * 32 + row];
                    if (m1 < M_) dst[m1] = vals1[r] + saux[w * 32 + 16 + row];
                }
            }
        } else {
            // final minima for this block's 128 gts: clamp + sum
            float s = 0.f;
            if (l15 == 0) {
                float vals0[4] = {c0.x, c0.y, c0.z, c0.w};
                float vals1[4] = {c1.x, c1.y, c1.z, c1.w};
                #pragma unroll
                for (int r = 0; r < 4; ++r) {
                    int row = quad * 4 + r;
                    s += fmaxf(vals0[r] + saux[w * 32 + row], 0.f);
                    s += fmaxf(vals1[r] + saux[w * 32 + 16 + row], 0.f);
                }
                saux[128 + w * 4 + quad] = s;
            }
            __syncthreads();
            if (tid == 0) {
                float t = 0.f;
                #pragma unroll
                for (int i = 0; i < 16; ++i) t += saux[128 + i];
                ws[WS_G2P + (bid - NB_P2GT)] = t;
            }
        }
    } else {
        // ---------------- fff pass 1 ----------------
        const int kb = bid - NB_P2GT - NB_GT2P;
        const int i  = kb * 256 + tid;
        float* red4 = saux;           // [0..3]
        float* sA   = saux + 8;       // [8..15]
        if (tid < B_) sA[tid] = 0.f;
        __syncthreads();

        float sE = 0.f, sG = 0.f, sMC = 0.f, sST = 0.f, sF = 0.f;
        if (i < B_ * M_) {
            const int b = i / M_;
            const int m = i - b * M_;
            const float* f = fff + (size_t)i * 3;
            float E = f[0], F = f[1], G = f[2];
            sE = E; sG = G;
            float A2  = fmaxf(E * G - F * F, 0.f);
            float inv = 1.f / (A2 + EPS_);
            sST = (E - G) * (E - G) * inv;
            sF  = F * F * inv;
            atomicAdd(&sA[b], sqrtf(A2));
            if ((b & 1) == 0) {
                const float* f2 = fff + ((size_t)(b + 1) * M_ + m) * 3;
                float dE = E - f2[0], dF = F - f2[1], dG = G - f2[2];
                sMC = dE * dE + 2.f * dF * dF + dG * dG;
            }
        }
        float rE  = block_sum256(sE,  red4);
        float rG  = block_sum256(sG,  red4);
        float rMC = block_sum256(sMC, red4);
        float rST = block_sum256(sST, red4);
        float rF  = block_sum256(sF,  red4);
        float* outp = ws + WS_F1P + (size_t)kb * 16;
        if (tid == 0) {
            outp[0] = rE; outp[1] = rG; outp[2] = rMC; outp[3] = rST; outp[4] = rF;
        }
        __syncthreads();
        if (tid < B_) outp[5 + tid] = sA[tid];
    }
}

// ============================================================================
// Kernel 2: p2gt min-over-z + fff pass 2 + last-block finalize.
// ============================================================================
__global__ void __launch_bounds__(256) k2_reduce(
        const float* __restrict__ fff, const float* __restrict__ A_gt,
        float* __restrict__ ws, float* __restrict__ out) {
    __shared__ float red4[4];
    __shared__ float bc2[2];
    const int bid = blockIdx.x;
    const int tid = threadIdx.x;
    float* redp = ws + WS_RED;
    const float* f1p = ws + WS_F1P;

    if (bid < NB_RP2) {
        const int o = bid * 256 + tid;               // [0,20224)
        float s = 0.f;
        if (o < 20000) {
            const float* src = ws + WS_P2GT + o;
            float m = src[0];
            m = fminf(m, src[20000]);
            m = fminf(m, src[40000]);
            m = fminf(m, src[60000]);
            s = fmaxf(m, 0.f);
        }
        float r = block_sum256(s, red4);
        if (tid == 0) redp[RO_P2 + bid] = r;
    } else {
        const int kb = bid - NB_RP2;
        float pe = 0.f, pg = 0.f;
        if (tid < 79) { pe = f1p[tid * 16 + 0]; pg = f1p[tid * 16 + 1]; }
        float rE = block_sum256(pe, red4);
        float rG = block_sum256(pg, red4);
        if (tid == 0) { bc2[0] = rE; bc2[1] = rG; }
        __syncthreads();
        const float mE = bc2[0] * (1.f / 20000.f);
        const float mG = bc2[1] * (1.f / 20000.f);

        const int i = kb * 256 + tid;
        float sEC = 0.f, sGC = 0.f;
        if (i < B_ * M_) {
            const float* f = fff + (size_t)i * 3;
            float E = f[0], F = f[1], G = f[2];
            float A2  = fmaxf(E * G - F * F, 0.f);
            float inv = 1.f / (A2 + EPS_);
            sEC = (E - mE) * (E - mE) * inv;
            sGC = (G - mG) * (G - mG) * inv;
        }
        float rEC = block_sum256(sEC, red4);
        float rGC = block_sum256(sGC, red4);
        if (tid == 0) { redp[RO_EC + kb] = rEC; redp[RO_GC + kb] = rGC; }
    }

    // ---- arrival counter; last block finalizes ----
    __syncthreads();
    if (tid == 0) __threadfence();
    __syncthreads();
    __shared__ unsigned old_s;
    if (tid == 0)
        old_s = __hip_atomic_fetch_add((unsigned*)(ws + WS_CNT), 1u,
                                       __ATOMIC_ACQ_REL, __HIP_MEMORY_SCOPE_AGENT);
    __syncthreads();
    if (old_s == (unsigned)(NB_K2 - 1)) {
        const float* g2p = ws + WS_G2P;
        float v;
        v = g2p[tid] + g2p[tid + 256];
        float sGT2P = block_sum256(v, red4);
        v = (tid < 79) ? redp[RO_P2 + tid] : 0.f;
        float sP2GT = block_sum256(v, red4);
        v = (tid < 79) ? redp[RO_EC + tid] : 0.f;
        float sEC = block_sum256(v, red4);
        v = (tid < 79) ? redp[RO_GC + tid] : 0.f;
        float sGC = block_sum256(v, red4);
        v = (tid < 79) ? f1p[tid * 16 + 2] : 0.f;
        float sMC = block_sum256(v, red4);
        v = (tid < 79) ? f1p[tid * 16 + 3] : 0.f;
        float sST = block_sum256(v, red4);
        v = (tid < 79) ? f1p[tid * 16 + 4] : 0.f;
        float sF = block_sum256(v, red4);
        float sAb[B_];
        #pragma unroll
        for (int b = 0; b < B_; ++b) {
            v = (tid < 79) ? f1p[tid * 16 + 5 + b] : 0.f;
            sAb[b] = block_sum256(v, red4);
        }
        if (tid == 0) {
            float L_chd = sP2GT * (1.f / 20000.f) + sGT2P * (1.f / 65536.f);
            float L_mc  = sMC * (1.f / 10000.f);
            float L_sc  = (sST + sF + sEC + sGC) * (1.f / 20000.f);
            float L_olap = 0.f;
            #pragma unroll
            for (int b = 0; b < B_; ++b) {
                float At = sAb[b] * (1.f / (float)SPP_);
                float r  = fmaxf(0.f, At - A_gt[b]);
                L_olap += r * r;
            }
            L_olap *= (1.f / (float)B_);
            out[0] = L_chd + L_mc + L_sc + L_olap;
        }
    }
}

extern "C" void kernel_launch(void* const* d_in, const int* in_sizes, int n_in,
                              void* d_out, int out_size, void* d_ws, size_t ws_size,
                              hipStream_t stream) {
    const float* pc_gt   = (const float*)d_in[0];   // (8, 8192, 3)
    const float* pc_pred = (const float*)d_in[1];   // (8, 2500, 3)
    const float* fff     = (const float*)d_in[2];   // (8, 2500, 3)
    const float* A_gt    = (const float*)d_in[3];   // (8,)
    float* ws  = (float*)d_ws;                      // ~330 KB used
    float* out = (float*)d_out;

    k1_main  <<<NB_K1, 256, 0, stream>>>(pc_gt, pc_pred, fff, ws);
    k2_reduce<<<NB_K2, 256, 0, stream>>>(fff, A_gt, ws, out);
}

// Round 7
// 107.556 us; speedup vs baseline: 1.1584x; 1.1305x over previous
//
#include <hip/hip_runtime.h>

// Problem constants (from reference: B=8, N=8192, M=2500, P=10)
#define B_   8
#define N_   8192
#define M_   2500
#define SPP_ 250
#define EPS_ 1e-20f
#define BIGF 1e30f

// ---- kernel-1 roles ----
// p2gt: 10 m-blocks (256 preds) x 8 b x 8 z-chunks (1024 gt)  = 640
// gt2p: 32 m-blocks (256 gts)  x 8 b x 2 z-chunks (1280 pred) = 512
#define NB_P2GT 640
#define NB_GT2P 512
#define NB_FFF1 79
#define NB_K1   (NB_P2GT + NB_GT2P + NB_FFF1)   // 1231

// ---- kernel-2 roles ----
#define NB_RG2P 256
#define NB_RP2  79
#define NB_FFF2 79
#define NB_K2   (NB_RG2P + NB_RP2 + NB_FFF2)    // 414

// ---- ws layout (floats) ----
#define WS_P2GT 0            // 8 z x 20000 partial minima (unclamped, norm-biased)
#define WS_GT2P 160000       // 2 z x 65536 partial minima
#define WS_F1P  291072       // 79 x 16 fff pass-1 partials
#define WS_RED  292336       // k2 partials: 256 g2p + 79 p2 + 79 EC + 79 GC
#define RO_G2P  0
#define RO_P2   256
#define RO_EC   335
#define RO_GC   414
#define WS_CNT  292829       // arrival counter (uint)

typedef __attribute__((ext_vector_type(8)))  short short8_t;
typedef __attribute__((ext_vector_type(4)))  float float4_t;

__device__ __forceinline__ unsigned pack_bf2(float lo, float hi) {
    unsigned a = __float_as_uint(lo);
    unsigned b = __float_as_uint(hi);
    a = (a + 0x7FFFu + ((a >> 16) & 1u)) >> 16;
    b = (b + 0x7FFFu + ((b >> 16) & 1u)) & 0xFFFF0000u;
    return a | b;
}
__device__ __forceinline__ short bf16s(float x) {
    unsigned a = __float_as_uint(x);
    return (short)((a + 0x7FFFu + ((a >> 16) & 1u)) >> 16);
}

__device__ __forceinline__ float wave_sum64(float v) {
    #pragma unroll
    for (int o = 32; o > 0; o >>= 1) v += __shfl_down(v, o, 64);
    return v;
}
__device__ __forceinline__ float block_sum256(float v, float* red4) {
    v = wave_sum64(v);
    int wid  = threadIdx.x >> 6;
    int lane = threadIdx.x & 63;
    if (lane == 0) red4[wid] = v;
    __syncthreads();
    float r = 0.f;
    if (threadIdx.x == 0) r = red4[0] + red4[1] + red4[2] + red4[3];
    __syncthreads();
    return r;
}

__device__ __forceinline__ void min4(float4_t& c, const float4_t d) {
    c.x = fminf(c.x, d.x); c.y = fminf(c.y, d.y);
    c.z = fminf(c.z, d.z); c.w = fminf(c.w, d.w);
}
// min over the 16 lanes of each quad (quad-local butterfly, masks < 16)
__device__ __forceinline__ void quad_min4(float4_t& c) {
    #pragma unroll
    for (int m = 1; m < 16; m <<= 1) {
        c.x = fminf(c.x, __shfl_xor(c.x, m, 64));
        c.y = fminf(c.y, __shfl_xor(c.y, m, 64));
        c.z = fminf(c.z, __shfl_xor(c.z, m, 64));
        c.w = fminf(c.w, __shfl_xor(c.w, m, 64));
    }
}

// ============================================================================
// Kernel 1: MFMA chamfer (both directions) + fff pass 1.
// Per wave: 4 A-tiles (64 rows). Per iter: one ds_read_b128 B-fragment feeds
// 4 MFMAs whose C operand is a loop-invariant fp32 row-norm bias tuple, so
// D = (-2 a.b + |b|^2) + |a|^2 = d^2 directly. 16 v_min per 1024 pairs.
// A[k>=4]=0 exactly, so B's k>=4 halves are finite garbage (duplicated pack).
// ============================================================================
__global__ void __launch_bounds__(256) k1_main(
        const float* __restrict__ gt, const float* __restrict__ pred,
        const float* __restrict__ fff, float* __restrict__ ws) {
    __shared__ uint4 spts[1280];              // {-2x,-2y | -2z,n2} duplicated
    __shared__ __align__(16) float saux[256]; // per-wave 64 row norms
    const int bid = blockIdx.x;
    const int tid = threadIdx.x;
    const int lane = tid & 63;
    const int w    = tid >> 6;
    const int quad = lane >> 4;
    const int l15  = lane & 15;

    if (bid == 0 && tid == 0) ((unsigned*)(ws + WS_CNT))[0] = 0u;

    if (bid < NB_P2GT + NB_GT2P) {
        const bool is_p2gt = bid < NB_P2GT;
        int b, mblk, z, ntiles, nstage, blim, alim;
        const float* apts; const float* bpts; float* dst;
        if (is_p2gt) {
            z = bid / 80; int rem = bid % 80;
            b = rem / 10; mblk = rem % 10;
            apts = pred + (size_t)b * M_ * 3;
            bpts = gt + ((size_t)b * N_ + (size_t)z * 1024) * 3;
            ntiles = 64; nstage = 1024; blim = 1024; alim = M_;
            dst = ws + WS_P2GT + (size_t)z * 20000 + b * M_;
        } else {
            int r = bid - NB_P2GT;
            z = r >> 8; int rem = r & 255;
            b = rem >> 5; mblk = rem & 31;
            apts = gt + (size_t)b * N_ * 3;
            bpts = pred + ((size_t)b * M_ + (size_t)z * 1280) * 3;
            ntiles = 80; nstage = 1280; blim = M_ - z * 1280; alim = N_;
            dst = ws + WS_GT2P + (size_t)z * 65536 + b * N_;
        }
        const int abase = mblk * 256 + w * 64;

        // ---- stage B points (bf16 packed, -2 folded, norm in w; dup halves)
        for (int i = tid; i < nstage; i += 256) {
            float x = 0.f, y = 0.f, zc = 0.f, n2 = BIGF;
            if (i < blim) {
                x = bpts[i * 3 + 0]; y = bpts[i * 3 + 1]; zc = bpts[i * 3 + 2];
                n2 = x * x + y * y + zc * zc;
            }
            uint4 q;
            q.x = pack_bf2(-2.f * x, -2.f * y);
            q.y = pack_bf2(-2.f * zc, n2);
            q.z = q.x; q.w = q.y;
            spts[i] = q;
        }

        // ---- A fragments: 4 tiles of 16 rows per wave; quad-0 lanes hold k=0..3
        short8_t af[4];
        #pragma unroll
        for (int t = 0; t < 4; ++t) af[t] = (short8_t){0,0,0,0,0,0,0,0};
        if (lane < 16) {
            #pragma unroll
            for (int t = 0; t < 4; ++t) {
                int m = abase + t * 16 + l15;
                int c = m < alim ? m : alim - 1;
                float x = apts[c*3+0], y = apts[c*3+1], zc = apts[c*3+2];
                af[t][0] = bf16s(x); af[t][1] = bf16s(y); af[t][2] = bf16s(zc);
                af[t][3] = (short)0x3F80;   // 1.0 bf16
                saux[w * 64 + t * 16 + l15] = x*x + y*y + zc*zc;
            }
        }
        __syncthreads();

        // ---- loop-invariant C bias tuples: rows quad*4+r of each tile
        const float4_t* bp = (const float4_t*)saux;
        float4_t bias[4];
        #pragma unroll
        for (int t = 0; t < 4; ++t) bias[t] = bp[w * 16 + t * 4 + quad];

        float4_t c[4];
        #pragma unroll
        for (int t = 0; t < 4; ++t) c[t] = (float4_t){BIGF, BIGF, BIGF, BIGF};

        const uint4* bptr = spts + l15;   // quads duplicate address = broadcast
        #pragma unroll 4
        for (int i = 0; i < ntiles; ++i) {
            short8_t bf = __builtin_bit_cast(short8_t, bptr[i * 16]);
            #pragma unroll
            for (int t = 0; t < 4; ++t) {
                float4_t d = __builtin_amdgcn_mfma_f32_16x16x32_bf16(
                                 af[t], bf, bias[t], 0, 0, 0);
                min4(c[t], d);
            }
        }
        #pragma unroll
        for (int t = 0; t < 4; ++t) quad_min4(c[t]);

        // ---- store: quad leaders write 4 consecutive rows per tile (16B)
        if (l15 == 0) {
            #pragma unroll
            for (int t = 0; t < 4; ++t) {
                int m0 = abase + t * 16 + quad * 4;
                if (m0 < alim)   // alim%4==0 -> groups never straddle
                    *(float4_t*)(dst + m0) = c[t];
            }
        }
    } else {
        // ---------------- fff pass 1 ----------------
        const int kb = bid - NB_P2GT - NB_GT2P;
        const int i  = kb * 256 + tid;
        float* red4 = saux;           // [0..3]
        float* sA   = saux + 8;       // [8..15]
        if (tid < B_) sA[tid] = 0.f;
        __syncthreads();

        float sE = 0.f, sG = 0.f, sMC = 0.f, sST = 0.f, sF = 0.f;
        if (i < B_ * M_) {
            const int b = i / M_;
            const int m = i - b * M_;
            const float* f = fff + (size_t)i * 3;
            float E = f[0], F = f[1], G = f[2];
            sE = E; sG = G;
            float A2  = fmaxf(E * G - F * F, 0.f);
            float inv = 1.f / (A2 + EPS_);
            sST = (E - G) * (E - G) * inv;
            sF  = F * F * inv;
            atomicAdd(&sA[b], sqrtf(A2));
            if ((b & 1) == 0) {
                const float* f2 = fff + ((size_t)(b + 1) * M_ + m) * 3;
                float dE = E - f2[0], dF = F - f2[1], dG = G - f2[2];
                sMC = dE * dE + 2.f * dF * dF + dG * dG;
            }
        }
        float rE  = block_sum256(sE,  red4);
        float rG  = block_sum256(sG,  red4);
        float rMC = block_sum256(sMC, red4);
        float rST = block_sum256(sST, red4);
        float rF  = block_sum256(sF,  red4);
        float* outp = ws + WS_F1P + (size_t)kb * 16;
        if (tid == 0) {
            outp[0] = rE; outp[1] = rG; outp[2] = rMC; outp[3] = rST; outp[4] = rF;
        }
        __syncthreads();
        if (tid < B_) outp[5 + tid] = sA[tid];
    }
}

// ============================================================================
// Kernel 2: min-over-z both directions + fff pass 2 + last-block finalize.
// ============================================================================
__global__ void __launch_bounds__(256) k2_reduce(
        const float* __restrict__ fff, const float* __restrict__ A_gt,
        float* __restrict__ ws, float* __restrict__ out) {
    __shared__ float red4[4];
    __shared__ float bc2[2];
    const int bid = blockIdx.x;
    const int tid = threadIdx.x;
    float* redp = ws + WS_RED;
    const float* f1p = ws + WS_F1P;

    if (bid < NB_RG2P) {
        const int o = bid * 256 + tid;               // [0,65536)
        const float* src = ws + WS_GT2P + o;
        float m = fminf(src[0], src[65536]);
        float r = block_sum256(fmaxf(m, 0.f), red4);
        if (tid == 0) redp[RO_G2P + bid] = r;
    } else if (bid < NB_RG2P + NB_RP2) {
        const int kb = bid - NB_RG2P;
        const int o = kb * 256 + tid;                // [0,20224)
        float s = 0.f;
        if (o < 20000) {
            const float* src = ws + WS_P2GT + o;
            float m = src[0];
            #pragma unroll
            for (int zz = 1; zz < 8; ++zz) m = fminf(m, src[zz * 20000]);
            s = fmaxf(m, 0.f);
        }
        float r = block_sum256(s, red4);
        if (tid == 0) redp[RO_P2 + kb] = r;
    } else {
        const int kb = bid - NB_RG2P - NB_RP2;
        float pe = 0.f, pg = 0.f;
        if (tid < 79) { pe = f1p[tid * 16 + 0]; pg = f1p[tid * 16 + 1]; }
        float rE = block_sum256(pe, red4);
        float rG = block_sum256(pg, red4);
        if (tid == 0) { bc2[0] = rE; bc2[1] = rG; }
        __syncthreads();
        const float mE = bc2[0] * (1.f / 20000.f);
        const float mG = bc2[1] * (1.f / 20000.f);

        const int i = kb * 256 + tid;
        float sEC = 0.f, sGC = 0.f;
        if (i < B_ * M_) {
            const float* f = fff + (size_t)i * 3;
            float E = f[0], F = f[1], G = f[2];
            float A2  = fmaxf(E * G - F * F, 0.f);
            float inv = 1.f / (A2 + EPS_);
            sEC = (E - mE) * (E - mE) * inv;
            sGC = (G - mG) * (G - mG) * inv;
        }
        float rEC = block_sum256(sEC, red4);
        float rGC = block_sum256(sGC, red4);
        if (tid == 0) { redp[RO_EC + kb] = rEC; redp[RO_GC + kb] = rGC; }
    }

    // ---- arrival counter; last block finalizes ----
    __syncthreads();
    if (tid == 0) __threadfence();
    __syncthreads();
    __shared__ unsigned old_s;
    if (tid == 0)
        old_s = __hip_atomic_fetch_add((unsigned*)(ws + WS_CNT), 1u,
                                       __ATOMIC_ACQ_REL, __HIP_MEMORY_SCOPE_AGENT);
    __syncthreads();
    if (old_s == (unsigned)(NB_K2 - 1)) {
        float v;
        v = redp[RO_G2P + tid];
        float sGT2P = block_sum256(v, red4);
        v = (tid < 79) ? redp[RO_P2 + tid] : 0.f;
        float sP2GT = block_sum256(v, red4);
        v = (tid < 79) ? redp[RO_EC + tid] : 0.f;
        float sEC = block_sum256(v, red4);
        v = (tid < 79) ? redp[RO_GC + tid] : 0.f;
        float sGC = block_sum256(v, red4);
        v = (tid < 79) ? f1p[tid * 16 + 2] : 0.f;
        float sMC = block_sum256(v, red4);
        v = (tid < 79) ? f1p[tid * 16 + 3] : 0.f;
        float sST = block_sum256(v, red4);
        v = (tid < 79) ? f1p[tid * 16 + 4] : 0.f;
        float sF = block_sum256(v, red4);
        float sAb[B_];
        #pragma unroll
        for (int b = 0; b < B_; ++b) {
            v = (tid < 79) ? f1p[tid * 16 + 5 + b] : 0.f;
            sAb[b] = block_sum256(v, red4);
        }
        if (tid == 0) {
            float L_chd = sP2GT * (1.f / 20000.f) + sGT2P * (1.f / 65536.f);
            float L_mc  = sMC * (1.f / 10000.f);
            float L_sc  = (sST + sF + sEC + sGC) * (1.f / 20000.f);
            float L_olap = 0.f;
            #pragma unroll
            for (int b = 0; b < B_; ++b) {
                float At = sAb[b] * (1.f / (float)SPP_);
                float r  = fmaxf(0.f, At - A_gt[b]);
                L_olap += r * r;
            }
            L_olap *= (1.f / (float)B_);
            out[0] = L_chd + L_mc + L_sc + L_olap;
        }
    }
}

extern "C" void kernel_launch(void* const* d_in, const int* in_sizes, int n_in,
                              void* d_out, int out_size, void* d_ws, size_t ws_size,
                              hipStream_t stream) {
    const float* pc_gt   = (const float*)d_in[0];   // (8, 8192, 3)
    const float* pc_pred = (const float*)d_in[1];   // (8, 2500, 3)
    const float* fff     = (const float*)d_in[2];   // (8, 2500, 3)
    const float* A_gt    = (const float*)d_in[3];   // (8,)
    float* ws  = (float*)d_ws;                      // ~1.2 MB used
    float* out = (float*)d_out;

    k1_main  <<<NB_K1, 256, 0, stream>>>(pc_gt, pc_pred, fff, ws);
    k2_reduce<<<NB_K2, 256, 0, stream>>>(fff, A_gt, ws, out);
}